// Round 1
// baseline (516.261 us; speedup 1.0000x reference)
//
#include <hip/hip_runtime.h>
#include <math.h>

#define SEQ 130
#define EMB 16
#define LIN 1039
#define LPAD 1040

__device__ __forceinline__ float dot4(const float4 a, const float4 b) {
    return a.x * b.x + a.y * b.y + a.z * b.z + a.w * b.w;
}

__global__ __launch_bounds__(256) void st_kernel(
    const float* __restrict__ x,
    const float* __restrict__ w_proj, const float* __restrict__ b_proj,
    const float* __restrict__ w_in,  const float* __restrict__ b_in,
    const float* __restrict__ w_out, const float* __restrict__ b_out,
    const float* __restrict__ ln1_g, const float* __restrict__ ln1_b,
    const float* __restrict__ w1,    const float* __restrict__ b1,
    const float* __restrict__ w2,    const float* __restrict__ b2,
    const float* __restrict__ ln2_g, const float* __restrict__ ln2_b,
    float* __restrict__ out)
{
    __shared__ __align__(16) float xs[LPAD];
    __shared__ __align__(16) float hS[SEQ][EMB];
    __shared__ __align__(16) float qS[SEQ][EMB];   // reused for final rows
    __shared__ __align__(16) float kS[SEQ][EMB];
    __shared__ __align__(16) float vS[SEQ][EMB];
    __shared__ float wprojS[EMB][9];               // pad 8->9 (bank spread)
    __shared__ __align__(16) float winS[48][EMB];
    __shared__ __align__(16) float woutS[EMB][EMB];
    __shared__ float bprojS[EMB], binS[48], boutS[EMB];
    __shared__ float w1S[EMB], w2S[EMB], b2S[EMB];
    __shared__ float ln1gS[EMB], ln1bS[EMB], ln2gS[EMB], ln2bS[EMB];
    __shared__ float b1S;
    __shared__ float psum[16][17];

    const int tid = threadIdx.x;
    const int b   = blockIdx.x;

    // ---- stage parameters into LDS ----
    if (tid < 128) wprojS[tid >> 3][tid & 7] = w_proj[tid];
    for (int i = tid; i < 768; i += 256) winS[i >> 4][i & 15] = w_in[i];
    woutS[tid >> 4][tid & 15] = w_out[tid];        // exactly 256 elements
    if (tid < EMB) {
        bprojS[tid] = b_proj[tid];
        boutS[tid]  = b_out[tid];
        w1S[tid]    = w1[tid];
        w2S[tid]    = w2[tid];
        b2S[tid]    = b2[tid];
        ln1gS[tid]  = ln1_g[tid];
        ln1bS[tid]  = ln1_b[tid];
        ln2gS[tid]  = ln2_g[tid];
        ln2bS[tid]  = ln2_b[tid];
    }
    if (tid < 48) binS[tid] = b_in[tid];
    if (tid == 0) b1S = b1[0];

    // ---- x row -> LDS (pad tail with 0) ----
    const float* xrow = x + (size_t)b * LIN;
    for (int i = tid; i < LPAD; i += 256)
        xs[i] = (i < LIN) ? xrow[i] : 0.0f;
    __syncthreads();

    // ---- phase 1: h = patches @ w_proj^T + b_proj + posenc ----
    for (int idx = tid; idx < SEQ * EMB; idx += 256) {
        int s = idx >> 4, e = idx & 15;
        float acc = bprojS[e];
        #pragma unroll
        for (int p = 0; p < 8; ++p)
            acc += xs[s * 8 + p] * wprojS[e][p];
        int i2 = e >> 1;
        float div = expf(-(float)(2 * i2) * 0.57564627324851149f); // ln(1e4)/16
        float ang = (float)s * div;
        acc += (e & 1) ? cosf(ang) : sinf(ang);
        hS[s][e] = acc;
    }
    __syncthreads();

    // ---- phase 2: qkv = h @ w_in^T + b_in ----
    for (int idx = tid; idx < SEQ * 12; idx += 256) {
        int s = idx / 12, f4 = (idx % 12) << 2;
        const float4* hr = (const float4*)hS[s];
        float4 h0 = hr[0], h1 = hr[1], h2 = hr[2], h3 = hr[3];
        #pragma unroll
        for (int j = 0; j < 4; ++j) {
            int f = f4 + j;
            const float4* wr = (const float4*)winS[f];
            float acc = binS[f] + dot4(h0, wr[0]) + dot4(h1, wr[1])
                                + dot4(h2, wr[2]) + dot4(h3, wr[3]);
            if (f < 16)      qS[s][f]      = acc * 0.25f;   // pre-scale q
            else if (f < 32) kS[s][f - 16] = acc;
            else             vS[s][f - 32] = acc;
        }
    }
    __syncthreads();

    // ---- phase 3: one q-row per thread, online softmax + epilogue ----
    if (tid < SEQ) {
        const int r = tid;
        float4 qv[4];
        {
            const float4* qr = (const float4*)qS[r];
            qv[0] = qr[0]; qv[1] = qr[1]; qv[2] = qr[2]; qv[3] = qr[3];
        }
        float m = -1e30f, l = 0.0f;
        float4 cv[4];
        cv[0] = cv[1] = cv[2] = cv[3] = make_float4(0.f, 0.f, 0.f, 0.f);

        for (int k0 = 0; k0 < SEQ; k0 += 2) {       // 130 is even: 65 iters
            const float4* kr0 = (const float4*)kS[k0];
            const float4* kr1 = (const float4*)kS[k0 + 1];
            float s0 = dot4(qv[0], kr0[0]) + dot4(qv[1], kr0[1])
                     + dot4(qv[2], kr0[2]) + dot4(qv[3], kr0[3]);
            float s1 = dot4(qv[0], kr1[0]) + dot4(qv[1], kr1[1])
                     + dot4(qv[2], kr1[2]) + dot4(qv[3], kr1[3]);
            float mn = fmaxf(m, fmaxf(s0, s1));
            float p0 = __expf(s0 - mn);
            float p1 = __expf(s1 - mn);
            float sc = __expf(m - mn);
            l = l * sc + p0 + p1;
            const float4* vr0 = (const float4*)vS[k0];
            const float4* vr1 = (const float4*)vS[k0 + 1];
            #pragma unroll
            for (int j = 0; j < 4; ++j) {
                float4 t0 = vr0[j], t1 = vr1[j];
                cv[j].x = cv[j].x * sc + p0 * t0.x + p1 * t1.x;
                cv[j].y = cv[j].y * sc + p0 * t0.y + p1 * t1.y;
                cv[j].z = cv[j].z * sc + p0 * t0.z + p1 * t1.z;
                cv[j].w = cv[j].w * sc + p0 * t0.w + p1 * t1.w;
            }
            m = mn;
        }
        float inv = 1.0f / l;
        float ctx[16];
        #pragma unroll
        for (int j = 0; j < 4; ++j) {
            ((float4*)ctx)[j] = make_float4(cv[j].x * inv, cv[j].y * inv,
                                            cv[j].z * inv, cv[j].w * inv);
        }
        // attn_out = ctx @ w_out^T + b_out ; residual
        float h2[16];
        {
            const float4* hr = (const float4*)hS[r];
            float4 hh0 = hr[0], hh1 = hr[1], hh2 = hr[2], hh3 = hr[3];
            float hrow[16];
            ((float4*)hrow)[0] = hh0; ((float4*)hrow)[1] = hh1;
            ((float4*)hrow)[2] = hh2; ((float4*)hrow)[3] = hh3;
            #pragma unroll
            for (int f = 0; f < 16; ++f) {
                const float4* wr = (const float4*)woutS[f];
                float acc = boutS[f]
                          + dot4(((const float4*)ctx)[0], wr[0])
                          + dot4(((const float4*)ctx)[1], wr[1])
                          + dot4(((const float4*)ctx)[2], wr[2])
                          + dot4(((const float4*)ctx)[3], wr[3]);
                h2[f] = hrow[f] + acc;
            }
        }
        // LN1
        float mean = 0.0f;
        #pragma unroll
        for (int e = 0; e < 16; ++e) mean += h2[e];
        mean *= (1.0f / 16.0f);
        float var = 0.0f;
        #pragma unroll
        for (int e = 0; e < 16; ++e) { float d = h2[e] - mean; var += d * d; }
        var *= (1.0f / 16.0f);
        float rstd = rsqrtf(var + 1e-5f);
        #pragma unroll
        for (int e = 0; e < 16; ++e)
            h2[e] = (h2[e] - mean) * rstd * ln1gS[e] + ln1bS[e];
        // FF: scalar bottleneck
        float ffa = b1S;
        #pragma unroll
        for (int e = 0; e < 16; ++e) ffa += h2[e] * w1S[e];
        ffa = fmaxf(ffa, 0.0f);
        float h3[16];
        #pragma unroll
        for (int e = 0; e < 16; ++e) h3[e] = h2[e] + (ffa * w2S[e] + b2S[e]);
        // LN2
        mean = 0.0f;
        #pragma unroll
        for (int e = 0; e < 16; ++e) mean += h3[e];
        mean *= (1.0f / 16.0f);
        var = 0.0f;
        #pragma unroll
        for (int e = 0; e < 16; ++e) { float d = h3[e] - mean; var += d * d; }
        var *= (1.0f / 16.0f);
        rstd = rsqrtf(var + 1e-5f);
        #pragma unroll
        for (int e = 0; e < 16; ++e)
            h3[e] = (h3[e] - mean) * rstd * ln2gS[e] + ln2bS[e];
        // store final row (reuse qS; each thread touches only its own row)
        float4* qdst = (float4*)qS[r];
        qdst[0] = ((float4*)h3)[0]; qdst[1] = ((float4*)h3)[1];
        qdst[2] = ((float4*)h3)[2]; qdst[3] = ((float4*)h3)[3];
    }
    __syncthreads();

    // ---- mean over rows ----
    {
        int e = tid & 15, part = tid >> 4;
        int r0 = part * 9;
        int r1 = min(SEQ, r0 + 9);
        float acc = 0.0f;
        for (int r = r0; r < r1; ++r) acc += qS[r][e];
        psum[part][e] = acc;
    }
    __syncthreads();
    if (tid < 16) {
        float acc = 0.0f;
        #pragma unroll
        for (int p = 0; p < 16; ++p) acc += psum[p][tid];
        out[(size_t)b * 16 + tid] = acc * (1.0f / 130.0f);
    }
}

extern "C" void kernel_launch(void* const* d_in, const int* in_sizes, int n_in,
                              void* d_out, int out_size, void* d_ws, size_t ws_size,
                              hipStream_t stream) {
    const float* x      = (const float*)d_in[0];
    const float* w_proj = (const float*)d_in[1];
    const float* b_proj = (const float*)d_in[2];
    const float* w_in   = (const float*)d_in[3];
    const float* b_in   = (const float*)d_in[4];
    const float* w_out  = (const float*)d_in[5];
    const float* b_out  = (const float*)d_in[6];
    const float* ln1_g  = (const float*)d_in[7];
    const float* ln1_b  = (const float*)d_in[8];
    const float* w1     = (const float*)d_in[9];
    const float* b1     = (const float*)d_in[10];
    const float* w2     = (const float*)d_in[11];
    const float* b2     = (const float*)d_in[12];
    const float* ln2_g  = (const float*)d_in[13];
    const float* ln2_b  = (const float*)d_in[14];

    int B = in_sizes[0] / LIN;
    st_kernel<<<B, 256, 0, stream>>>(x, w_proj, b_proj, w_in, b_in,
                                     w_out, b_out, ln1_g, ln1_b,
                                     w1, b1, w2, b2, ln2_g, ln2_b,
                                     (float*)d_out);
}

// Round 2
// 316.065 us; speedup vs baseline: 1.6334x; 1.6334x over previous
//
#include <hip/hip_runtime.h>
#include <math.h>

#define SEQ 130
#define SPAD 144      // 9 tiles of 16
#define EMB 16
#define LIN 1039
#define LPAD 1040
#define FP 20         // f16 row pad (halves): 40B rows -> conflict-free frags
#define CP 17         // ctx row pad (floats)

typedef __attribute__((ext_vector_type(4))) _Float16 half4v;
typedef __attribute__((ext_vector_type(4))) float float4v;

__device__ __forceinline__ float dot4(const float4 a, const float4 b) {
    return a.x * b.x + a.y * b.y + a.z * b.z + a.w * b.w;
}

__global__ __launch_bounds__(256) void st_kernel(
    const float* __restrict__ x,
    const float* __restrict__ w_proj, const float* __restrict__ b_proj,
    const float* __restrict__ w_in,  const float* __restrict__ b_in,
    const float* __restrict__ w_out, const float* __restrict__ b_out,
    const float* __restrict__ ln1_g, const float* __restrict__ ln1_b,
    const float* __restrict__ w1,    const float* __restrict__ b1,
    const float* __restrict__ w2,    const float* __restrict__ b2,
    const float* __restrict__ ln2_g, const float* __restrict__ ln2_b,
    float* __restrict__ out)
{
    __shared__ __align__(16) float xs[LPAD];
    __shared__ __align__(16) float hS[SEQ][EMB];
    __shared__ __align__(16) _Float16 qF[SPAD][FP];   // pre-scaled by 0.25
    __shared__ __align__(16) _Float16 kF[SPAD][FP];
    __shared__ __align__(16) _Float16 vF[SPAD][FP];
    __shared__ __align__(16) float ctxS[SEQ][CP];     // ctx, then final rows
    __shared__ float wprojS[EMB][9];
    __shared__ __align__(16) float winS[48][EMB];
    __shared__ __align__(16) float woutS[EMB][EMB];
    __shared__ float bprojS[EMB], binS[48], boutS[EMB];
    __shared__ float w1S[EMB], w2S[EMB], b2S[EMB];
    __shared__ float ln1gS[EMB], ln1bS[EMB], ln2gS[EMB], ln2bS[EMB];
    __shared__ float b1S;
    __shared__ float psum[16][17];

    const int tid = threadIdx.x;
    const int b   = blockIdx.x;

    // ---- stage parameters into LDS ----
    if (tid < 128) wprojS[tid >> 3][tid & 7] = w_proj[tid];
    for (int i = tid; i < 768; i += 256) winS[i >> 4][i & 15] = w_in[i];
    woutS[tid >> 4][tid & 15] = w_out[tid];
    if (tid < EMB) {
        bprojS[tid] = b_proj[tid];
        boutS[tid]  = b_out[tid];
        w1S[tid]    = w1[tid];
        w2S[tid]    = w2[tid];
        b2S[tid]    = b2[tid];
        ln1gS[tid]  = ln1_g[tid];
        ln1bS[tid]  = ln1_b[tid];
        ln2gS[tid]  = ln2_g[tid];
        ln2bS[tid]  = ln2_b[tid];
    }
    if (tid < 48) binS[tid] = b_in[tid];
    if (tid == 0) b1S = b1[0];

    // zero f16 pad rows 130..143 (dead q rows / masked k rows / V zero for p=0)
    for (int i = tid; i < (SPAD - SEQ) * FP; i += 256) {
        int r = SEQ + i / FP, c = i % FP;
        qF[r][c] = (_Float16)0.0f;
        kF[r][c] = (_Float16)0.0f;
        vF[r][c] = (_Float16)0.0f;
    }

    // ---- x row -> LDS (pad tail with 0) ----
    const float* xrow = x + (size_t)b * LIN;
    for (int i = tid; i < LPAD; i += 256)
        xs[i] = (i < LIN) ? xrow[i] : 0.0f;
    __syncthreads();

    // ---- phase 1: h = patches @ w_proj^T + b_proj + posenc ----
    for (int idx = tid; idx < SEQ * EMB; idx += 256) {
        int s = idx >> 4, e = idx & 15;
        float acc = bprojS[e];
        #pragma unroll
        for (int p = 0; p < 8; ++p)
            acc += xs[s * 8 + p] * wprojS[e][p];
        int i2 = e >> 1;
        float div = expf(-(float)(2 * i2) * 0.57564627324851149f);
        float ang = (float)s * div;
        acc += (e & 1) ? cosf(ang) : sinf(ang);
        hS[s][e] = acc;
    }
    __syncthreads();

    // ---- phase 2: qkv = h @ w_in^T + b_in -> f16 padded LDS ----
    for (int idx = tid; idx < SEQ * 12; idx += 256) {
        int s = idx / 12, f4 = (idx % 12) << 2;
        const float4* hr = (const float4*)hS[s];
        float4 h0 = hr[0], h1 = hr[1], h2 = hr[2], h3 = hr[3];
        #pragma unroll
        for (int j = 0; j < 4; ++j) {
            int f = f4 + j;
            const float4* wr = (const float4*)winS[f];
            float acc = binS[f] + dot4(h0, wr[0]) + dot4(h1, wr[1])
                                + dot4(h2, wr[2]) + dot4(h3, wr[3]);
            if (f < 16)      qF[s][f]      = (_Float16)(acc * 0.25f);
            else if (f < 32) kF[s][f - 16] = (_Float16)acc;
            else             vF[s][f - 32] = (_Float16)acc;
        }
    }
    __syncthreads();

    // ---- phase 3: MFMA flash attention ----
    // wave w owns q-tiles {w, w+4, w+8(if w==0)}; 9 tiles of 16 q-rows.
    // S^T = mfma(A=K, B=Q^T): lane (g=lane>>4, c=lane&15), reg j holds
    //   S[q = qt*16+c][k = kt*16+4g+j]  -> softmax state per row c is LOCAL.
    // ctx^T = mfma(A=V^T, B=P^T): reg j holds ctx[q = qt*16+c][e = 4g+j].
    {
        const int lane = tid & 63;
        const int wv   = tid >> 6;
        const int c    = lane & 15;
        const int g    = lane >> 4;
        const int qt0 = wv, qt1 = wv + 4, qt2 = wv + 8;   // qt2 valid iff wv==0
        const float4v zero4 = {0.0f, 0.0f, 0.0f, 0.0f};

        half4v qf0 = *(const half4v*)&qF[qt0 * 16 + c][4 * g];
        half4v qf1 = *(const half4v*)&qF[qt1 * 16 + c][4 * g];
        half4v qf2 = (wv == 0) ? *(const half4v*)&qF[qt2 * 16 + c][4 * g]
                               : (half4v){0, 0, 0, 0};

        float4v O0 = zero4, O1 = zero4, O2 = zero4;
        float m0 = -1e30f, m1 = -1e30f, m2 = -1e30f;
        float l0 = 0.0f, l1 = 0.0f, l2 = 0.0f;

        for (int kt = 0; kt < 9; ++kt) {
            const half4v kf = *(const half4v*)&kF[kt * 16 + c][4 * g];
            half4v vf;
            #pragma unroll
            for (int j = 0; j < 4; ++j)
                vf[j] = vF[kt * 16 + 4 * g + j][c];

#define ATTN_STEP(QF, O, M, L) do {                                           \
            float4v s4 = __builtin_amdgcn_mfma_f32_16x16x16f16(                \
                             kf, QF, zero4, 0, 0, 0);                          \
            if (kt == 8) {                                                     \
                s4[2] = -1e30f; s4[3] = -1e30f;                                \
                if (g > 0) { s4[0] = -1e30f; s4[1] = -1e30f; }                 \
            }                                                                  \
            float pm = fmaxf(fmaxf(s4[0], s4[1]), fmaxf(s4[2], s4[3]));        \
            pm = fmaxf(pm, __shfl_xor(pm, 16));                                \
            pm = fmaxf(pm, __shfl_xor(pm, 32));                                \
            float mn = fmaxf(M, pm);                                           \
            float sc = __expf(M - mn);                                         \
            float p0 = __expf(s4[0] - mn), p1 = __expf(s4[1] - mn);            \
            float p2 = __expf(s4[2] - mn), p3 = __expf(s4[3] - mn);            \
            float ps = (p0 + p1) + (p2 + p3);                                  \
            ps += __shfl_xor(ps, 16);                                          \
            ps += __shfl_xor(ps, 32);                                          \
            L = L * sc + ps;                                                   \
            M = mn;                                                            \
            O = O * sc;                                                        \
            half4v pf = {(_Float16)p0, (_Float16)p1,                           \
                         (_Float16)p2, (_Float16)p3};                          \
            O = __builtin_amdgcn_mfma_f32_16x16x16f16(vf, pf, O, 0, 0, 0);     \
        } while (0)

            ATTN_STEP(qf0, O0, m0, l0);
            ATTN_STEP(qf1, O1, m1, l1);
            if (wv == 0) ATTN_STEP(qf2, O2, m2, l2);
#undef ATTN_STEP
        }

        // normalize + write ctx (rows >= SEQ discarded)
        {
            float inv = 1.0f / l0;
            int row = qt0 * 16 + c;
            #pragma unroll
            for (int j = 0; j < 4; ++j) ctxS[row][4 * g + j] = O0[j] * inv;
        }
        {
            float inv = 1.0f / l1;
            int row = qt1 * 16 + c;
            if (row < SEQ) {
                #pragma unroll
                for (int j = 0; j < 4; ++j) ctxS[row][4 * g + j] = O1[j] * inv;
            }
        }
        if (wv == 0) {
            float inv = 1.0f / l2;
            int row = qt2 * 16 + c;
            if (row < SEQ) {
                #pragma unroll
                for (int j = 0; j < 4; ++j) ctxS[row][4 * g + j] = O2[j] * inv;
            }
        }
    }
    __syncthreads();

    // ---- epilogue: one q-row per thread ----
    if (tid < SEQ) {
        const int r = tid;
        float ctx[16];
        #pragma unroll
        for (int e = 0; e < 16; ++e) ctx[e] = ctxS[r][e];

        float h2[16];
        {
            const float4* hr = (const float4*)hS[r];
            float4 hh0 = hr[0], hh1 = hr[1], hh2 = hr[2], hh3 = hr[3];
            float hrow[16];
            ((float4*)hrow)[0] = hh0; ((float4*)hrow)[1] = hh1;
            ((float4*)hrow)[2] = hh2; ((float4*)hrow)[3] = hh3;
            #pragma unroll
            for (int f = 0; f < 16; ++f) {
                const float4* wr = (const float4*)woutS[f];
                float acc = boutS[f]
                          + dot4(((const float4*)ctx)[0], wr[0])
                          + dot4(((const float4*)ctx)[1], wr[1])
                          + dot4(((const float4*)ctx)[2], wr[2])
                          + dot4(((const float4*)ctx)[3], wr[3]);
                h2[f] = hrow[f] + acc;
            }
        }
        // LN1
        float mean = 0.0f;
        #pragma unroll
        for (int e = 0; e < 16; ++e) mean += h2[e];
        mean *= (1.0f / 16.0f);
        float var = 0.0f;
        #pragma unroll
        for (int e = 0; e < 16; ++e) { float d = h2[e] - mean; var += d * d; }
        var *= (1.0f / 16.0f);
        float rstd = rsqrtf(var + 1e-5f);
        #pragma unroll
        for (int e = 0; e < 16; ++e)
            h2[e] = (h2[e] - mean) * rstd * ln1gS[e] + ln1bS[e];
        // FF
        float ffa = b1S;
        #pragma unroll
        for (int e = 0; e < 16; ++e) ffa += h2[e] * w1S[e];
        ffa = fmaxf(ffa, 0.0f);
        float h3[16];
        #pragma unroll
        for (int e = 0; e < 16; ++e) h3[e] = h2[e] + (ffa * w2S[e] + b2S[e]);
        // LN2
        mean = 0.0f;
        #pragma unroll
        for (int e = 0; e < 16; ++e) mean += h3[e];
        mean *= (1.0f / 16.0f);
        var = 0.0f;
        #pragma unroll
        for (int e = 0; e < 16; ++e) { float d = h3[e] - mean; var += d * d; }
        var *= (1.0f / 16.0f);
        rstd = rsqrtf(var + 1e-5f);
        #pragma unroll
        for (int e = 0; e < 16; ++e)
            h3[e] = (h3[e] - mean) * rstd * ln2gS[e] + ln2bS[e];
        // store final row back into ctxS (own row only)
        #pragma unroll
        for (int e = 0; e < 16; ++e) ctxS[r][e] = h3[e];
    }
    __syncthreads();

    // ---- mean over rows ----
    {
        int e = tid & 15, part = tid >> 4;
        int r0 = part * 9;
        int r1 = min(SEQ, r0 + 9);
        float acc = 0.0f;
        for (int r = r0; r < r1; ++r) acc += ctxS[r][e];
        psum[part][e] = acc;
    }
    __syncthreads();
    if (tid < 16) {
        float acc = 0.0f;
        #pragma unroll
        for (int p = 0; p < 16; ++p) acc += psum[p][tid];
        out[(size_t)b * 16 + tid] = acc * (1.0f / 130.0f);
    }
}

extern "C" void kernel_launch(void* const* d_in, const int* in_sizes, int n_in,
                              void* d_out, int out_size, void* d_ws, size_t ws_size,
                              hipStream_t stream) {
    const float* x      = (const float*)d_in[0];
    const float* w_proj = (const float*)d_in[1];
    const float* b_proj = (const float*)d_in[2];
    const float* w_in   = (const float*)d_in[3];
    const float* b_in   = (const float*)d_in[4];
    const float* w_out  = (const float*)d_in[5];
    const float* b_out  = (const float*)d_in[6];
    const float* ln1_g  = (const float*)d_in[7];
    const float* ln1_b  = (const float*)d_in[8];
    const float* w1     = (const float*)d_in[9];
    const float* b1     = (const float*)d_in[10];
    const float* w2     = (const float*)d_in[11];
    const float* b2     = (const float*)d_in[12];
    const float* ln2_g  = (const float*)d_in[13];
    const float* ln2_b  = (const float*)d_in[14];

    int B = in_sizes[0] / LIN;
    st_kernel<<<B, 256, 0, stream>>>(x, w_proj, b_proj, w_in, b_in,
                                     w_out, b_out, ln1_g, ln1_b,
                                     w1, b1, w2, b2, ln2_g, ln2_b,
                                     (float*)d_out);
}

// Round 8
// 135.517 us; speedup vs baseline: 3.8096x; 2.3323x over previous
//
#include <hip/hip_runtime.h>
#include <math.h>

#define SEQ 130
#define SPAD 144      // 9 tiles of 16
#define EMB 16
#define LIN 1039
#define LPAD 1040
#define FP 20         // f16 row pad (halves): 40B rows -> 4-way (BW-floor) frags

typedef __attribute__((ext_vector_type(4))) _Float16 half4v;
typedef __attribute__((ext_vector_type(4))) float float4v;

// ---- posenc (+ b_proj folded) table: computed once per launch into d_ws ----
__global__ void pe_kernel(const float* __restrict__ b_proj, float2* __restrict__ pe) {
    int idx = blockIdx.x * 256 + threadIdx.x;
    if (idx < SEQ * 8) {
        int s = idx >> 3, i = idx & 7;
        float div = expf(-(float)(2 * i) * 0.57564627324851149f); // ln(1e4)/16
        float ang = (float)s * div;
        pe[idx] = make_float2(sinf(ang) + b_proj[2 * i],
                              cosf(ang) + b_proj[2 * i + 1]);
    }
}

__global__ __launch_bounds__(256) void st_kernel(
    const float* __restrict__ x,
    const float* __restrict__ w_proj,
    const float* __restrict__ w_in,  const float* __restrict__ b_in,
    const float* __restrict__ w_out, const float* __restrict__ b_out,
    const float* __restrict__ ln1_g, const float* __restrict__ ln1_b,
    const float* __restrict__ w1,    const float* __restrict__ b1,
    const float* __restrict__ w2,    const float* __restrict__ b2,
    const float* __restrict__ ln2_g, const float* __restrict__ ln2_b,
    const float2* __restrict__ pe,
    float* __restrict__ out)
{
    __shared__ __align__(16) float xs[LPAD];
    __shared__ __align__(8) _Float16 hF[SPAD][FP];
    __shared__ __align__(8) _Float16 kF[SPAD][FP];
    __shared__ __align__(8) _Float16 vF[SPAD][FP];
    __shared__ __align__(8) _Float16 winF[48][FP];
    __shared__ __align__(8) _Float16 woutF[16][FP];
    __shared__ float wprojS[EMB][9];
    __shared__ float binS[48];
    __shared__ float boutS[16], w1S[16], w2S[16], b2S[16];
    __shared__ float ln1gS[16], ln1bS[16], ln2gS[16], ln2bS[16];
    __shared__ float b1S;
    __shared__ float psum[4][16];

    const int tid = threadIdx.x;
    const int b   = blockIdx.x;

    // ---- stage parameters ----
    if (tid < 128) wprojS[tid >> 3][tid & 7] = w_proj[tid];
    for (int i = tid; i < 384; i += 256) {          // w_in -> f16 (q rows ×0.25)
        int f = i >> 3, ep = i & 7;
        float sc = (f < 16) ? 0.25f : 1.0f;
        union { _Float16 h[2]; unsigned u; } pk;
        pk.h[0] = (_Float16)(w_in[f * 16 + 2 * ep] * sc);
        pk.h[1] = (_Float16)(w_in[f * 16 + 2 * ep + 1] * sc);
        *(unsigned*)&winF[f][2 * ep] = pk.u;
    }
    if (tid < 128) {                                 // w_out -> f16
        int f = tid >> 3, ep = tid & 7;
        union { _Float16 h[2]; unsigned u; } pk;
        pk.h[0] = (_Float16)w_out[f * 16 + 2 * ep];
        pk.h[1] = (_Float16)w_out[f * 16 + 2 * ep + 1];
        *(unsigned*)&woutF[f][2 * ep] = pk.u;
    }
    if (tid < 48) binS[tid] = b_in[tid] * ((tid < 16) ? 0.25f : 1.0f);
    if (tid >= 64 && tid < 80) {
        int e = tid - 64;
        boutS[e] = b_out[e]; w1S[e] = w1[e]; w2S[e] = w2[e]; b2S[e] = b2[e];
    }
    if (tid >= 80 && tid < 96) {
        int e = tid - 80;
        ln1gS[e] = ln1_g[e]; ln1bS[e] = ln1_b[e];
        ln2gS[e] = ln2_g[e]; ln2bS[e] = ln2_b[e];
    }
    if (tid == 96) b1S = b1[0];
    if (tid < 140) {                                 // zero hF pad rows 130..143
        int r = SEQ + tid / 10, w = tid % 10;
        *(unsigned*)&hF[r][2 * w] = 0u;
    }
    const float* xrow = x + (size_t)b * LIN;
    for (int i = tid; i < LPAD; i += 256) xs[i] = (i < LIN) ? xrow[i] : 0.0f;
    __syncthreads();

    // ---- phase 1: h = patches @ w_proj^T + (posenc + b_proj) -> f16 ----
    for (int idx = tid; idx < SEQ * 8; idx += 256) {
        int s = idx >> 3, i = idx & 7;
        const float* xp = &xs[s * 8];
        float a0 = 0.f, a1 = 0.f;
        #pragma unroll
        for (int p = 0; p < 8; ++p) {
            float xv = xp[p];
            a0 += xv * wprojS[2 * i][p];
            a1 += xv * wprojS[2 * i + 1][p];
        }
        float2 pp = pe[idx];
        a0 += pp.x; a1 += pp.y;
        union { _Float16 h[2]; unsigned u; } pk;
        pk.h[0] = (_Float16)a0; pk.h[1] = (_Float16)a1;
        *(unsigned*)&hF[s][2 * i] = pk.u;
    }
    __syncthreads();

    // ---- lane geometry & per-lane param regs ----
    const int lane = tid & 63;
    const int wv   = tid >> 6;
    const int c    = lane & 15;
    const int g    = lane >> 4;
    const float4v zero4 = {0.f, 0.f, 0.f, 0.f};

    float bqR[4], bkR[4], bvR[4], boR[4];
    float ln1gR[4], ln1bR[4], ln2gR[4], ln2bR[4], w1R[4], w2R[4], b2R[4];
    #pragma unroll
    for (int j = 0; j < 4; ++j) {
        int f = 4 * g + j;
        bqR[j] = binS[f]; bkR[j] = binS[16 + f]; bvR[j] = binS[32 + f];
        boR[j] = boutS[f];
        ln1gR[j] = ln1gS[f]; ln1bR[j] = ln1bS[f];
        ln2gR[j] = ln2gS[f]; ln2bR[j] = ln2bS[f];
        w1R[j] = w1S[f]; w2R[j] = w2S[f]; b2R[j] = b2S[f];
    }
    float b1v = b1S;

    // ---- phase 2: qkv via MFMA; q stays in regs, k/v -> LDS ----
    // D = mfma(A = w_in f-tile, B = h^T tile): reg j = qkv[s=st*16+c][f=4g+j]
    half4v hf0, hf1, hf2, qf0, qf1, qf2;

#define QKV_TILE(T, ST) do {                                                   \
        int row = (ST) * 16 + c;                                               \
        hf##T = *(const half4v*)&hF[row][4 * g];                               \
        float4v dq = __builtin_amdgcn_mfma_f32_16x16x16f16(                    \
            *(const half4v*)&winF[c][4 * g],      hf##T, zero4, 0, 0, 0);      \
        float4v dk = __builtin_amdgcn_mfma_f32_16x16x16f16(                    \
            *(const half4v*)&winF[16 + c][4 * g], hf##T, zero4, 0, 0, 0);      \
        float4v dv = __builtin_amdgcn_mfma_f32_16x16x16f16(                    \
            *(const half4v*)&winF[32 + c][4 * g], hf##T, zero4, 0, 0, 0);      \
        half4v kh, vh;                                                         \
        _Pragma("unroll") for (int j = 0; j < 4; ++j) {                        \
            qf##T[j] = (_Float16)(dq[j] + bqR[j]);                             \
            kh[j]    = (_Float16)(dk[j] + bkR[j]);                             \
            vh[j]    = (_Float16)(dv[j] + bvR[j]);                             \
        }                                                                      \
        *(half4v*)&kF[row][4 * g] = kh;                                        \
        *(half4v*)&vF[row][4 * g] = vh;                                        \
    } while (0)

    QKV_TILE(0, wv);
    QKV_TILE(1, wv + 4);
    if (wv == 0) { QKV_TILE(2, 8); } else { qf2 = qf0; hf2 = hf0; }
    __syncthreads();

    // ---- phase 3: MFMA flash attention (q-tiles wv, wv+4, [8 if wv==0]) ----
    float4v O0 = zero4, O1 = zero4, O2 = zero4;
    float m0 = -1e30f, m1 = -1e30f, m2 = -1e30f;
    float l0 = 0.f, l1 = 0.f, l2 = 0.f;

    for (int kt = 0; kt < 9; ++kt) {
        const half4v kf = *(const half4v*)&kF[kt * 16 + c][4 * g];
        half4v vf;
        #pragma unroll
        for (int j = 0; j < 4; ++j) vf[j] = vF[kt * 16 + 4 * g + j][c];

#define ATTN_STEP(QF, O, M, L) do {                                            \
            float4v s4 = __builtin_amdgcn_mfma_f32_16x16x16f16(                \
                             kf, QF, zero4, 0, 0, 0);                          \
            if (kt == 8) {                                                     \
                s4[2] = -1e30f; s4[3] = -1e30f;                                \
                if (g > 0) { s4[0] = -1e30f; s4[1] = -1e30f; }                 \
            }                                                                  \
            float pm = fmaxf(fmaxf(s4[0], s4[1]), fmaxf(s4[2], s4[3]));        \
            pm = fmaxf(pm, __shfl_xor(pm, 16));                                \
            pm = fmaxf(pm, __shfl_xor(pm, 32));                                \
            float mn = fmaxf(M, pm);                                           \
            float sc = __expf(M - mn);                                         \
            float p0 = __expf(s4[0] - mn), p1 = __expf(s4[1] - mn);            \
            float p2 = __expf(s4[2] - mn), p3 = __expf(s4[3] - mn);            \
            float ps = (p0 + p1) + (p2 + p3);                                  \
            ps += __shfl_xor(ps, 16);                                          \
            ps += __shfl_xor(ps, 32);                                          \
            L = L * sc + ps;                                                   \
            M = mn;                                                            \
            O = O * sc;                                                        \
            half4v pf = {(_Float16)p0, (_Float16)p1,                           \
                         (_Float16)p2, (_Float16)p3};                          \
            O = __builtin_amdgcn_mfma_f32_16x16x16f16(vf, pf, O, 0, 0, 0);     \
        } while (0)

        ATTN_STEP(qf0, O0, m0, l0);
        ATTN_STEP(qf1, O1, m1, l1);
        if (wv == 0) ATTN_STEP(qf2, O2, m2, l2);
#undef ATTN_STEP
    }

    // ---- epilogue: MFMA attn_out + shuffle-LN, accumulate row-mean ----
    float acc[4] = {0.f, 0.f, 0.f, 0.f};

#define EPILOGUE(T, ST, ON) do { if (ON) {                                     \
        float inv = 1.0f / l##T;                                               \
        half4v cf;                                                             \
        _Pragma("unroll") for (int j = 0; j < 4; ++j)                          \
            cf[j] = (_Float16)(O##T[j] * inv);                                 \
        float4v AO = __builtin_amdgcn_mfma_f32_16x16x16f16(                    \
            *(const half4v*)&woutF[c][4 * g], cf, zero4, 0, 0, 0);             \
        float h2[4], h3[4];                                                    \
        _Pragma("unroll") for (int j = 0; j < 4; ++j)                          \
            h2[j] = (float)hf##T[j] + AO[j] + boR[j];                          \
        float s1 = h2[0] + h2[1] + h2[2] + h2[3];                              \
        s1 += __shfl_xor(s1, 16); s1 += __shfl_xor(s1, 32);                    \
        float mean = s1 * 0.0625f;                                             \
        float vv = 0.f;                                                        \
        _Pragma("unroll") for (int j = 0; j < 4; ++j) {                        \
            float d = h2[j] - mean; vv += d * d; }                             \
        vv += __shfl_xor(vv, 16); vv += __shfl_xor(vv, 32);                    \
        float rstd = rsqrtf(vv * 0.0625f + 1e-5f);                             \
        _Pragma("unroll") for (int j = 0; j < 4; ++j)                          \
            h2[j] = (h2[j] - mean) * rstd * ln1gR[j] + ln1bR[j];               \
        float fa = h2[0]*w1R[0] + h2[1]*w1R[1] + h2[2]*w1R[2] + h2[3]*w1R[3];  \
        fa += __shfl_xor(fa, 16); fa += __shfl_xor(fa, 32);                    \
        float ffa = fmaxf(fa + b1v, 0.f);                                      \
        _Pragma("unroll") for (int j = 0; j < 4; ++j)                          \
            h3[j] = h2[j] + ffa * w2R[j] + b2R[j];                             \
        float s2 = h3[0] + h3[1] + h3[2] + h3[3];                              \
        s2 += __shfl_xor(s2, 16); s2 += __shfl_xor(s2, 32);                    \
        float mean2 = s2 * 0.0625f;                                            \
        float v2 = 0.f;                                                        \
        _Pragma("unroll") for (int j = 0; j < 4; ++j) {                        \
            float d = h3[j] - mean2; v2 += d * d; }                            \
        v2 += __shfl_xor(v2, 16); v2 += __shfl_xor(v2, 32);                    \
        float rstd2 = rsqrtf(v2 * 0.0625f + 1e-5f);                            \
        if (((ST) * 16 + c) < SEQ) {                                           \
            _Pragma("unroll") for (int j = 0; j < 4; ++j)                      \
                acc[j] += (h3[j] - mean2) * rstd2 * ln2gR[j] + ln2bR[j];       \
        } } } while (0)

    EPILOGUE(0, wv, true);
    EPILOGUE(1, wv + 4, true);
    EPILOGUE(2, 8, (wv == 0));
#undef EPILOGUE
#undef QKV_TILE

    // reduce row-sums across the 16 c-lanes (strides 1,2,4,8 stay within g)
    #pragma unroll
    for (int off = 1; off < 16; off <<= 1) {
        #pragma unroll
        for (int j = 0; j < 4; ++j) acc[j] += __shfl_xor(acc[j], off);
    }
    if (c == 0) {
        #pragma unroll
        for (int j = 0; j < 4; ++j) psum[wv][4 * g + j] = acc[j];
    }
    __syncthreads();
    if (tid < 16) {
        float s = psum[0][tid] + psum[1][tid] + psum[2][tid] + psum[3][tid];
        out[(size_t)b * 16 + tid] = s * (1.0f / 130.0f);
    }
}

extern "C" void kernel_launch(void* const* d_in, const int* in_sizes, int n_in,
                              void* d_out, int out_size, void* d_ws, size_t ws_size,
                              hipStream_t stream) {
    const float* x      = (const float*)d_in[0];
    const float* w_proj = (const float*)d_in[1];
    const float* b_proj = (const float*)d_in[2];
    const float* w_in   = (const float*)d_in[3];
    const float* b_in   = (const float*)d_in[4];
    const float* w_out  = (const float*)d_in[5];
    const float* b_out  = (const float*)d_in[6];
    const float* ln1_g  = (const float*)d_in[7];
    const float* ln1_b  = (const float*)d_in[8];
    const float* w1     = (const float*)d_in[9];
    const float* b1     = (const float*)d_in[10];
    const float* w2     = (const float*)d_in[11];
    const float* b2     = (const float*)d_in[12];
    const float* ln2_g  = (const float*)d_in[13];
    const float* ln2_b  = (const float*)d_in[14];

    float2* pe = (float2*)d_ws;
    pe_kernel<<<(SEQ * 8 + 255) / 256, 256, 0, stream>>>(b_proj, pe);

    int B = in_sizes[0] / LIN;
    st_kernel<<<B, 256, 0, stream>>>(x, w_proj, w_in, b_in,
                                     w_out, b_out, ln1_g, ln1_b,
                                     w1, b1, w2, b2, ln2_g, ln2_b,
                                     pe, (float*)d_out);
}